// Round 1
// baseline (697.760 us; speedup 1.0000x reference)
//
#include <hip/hip_runtime.h>
#include <stdint.h>
#include <math.h>

#define GM 8192   // rows of x / out
#define GN 4096   // D_OUT
#define GK 4096   // D_IN
#define BM 128
#define BN 128
#define BK 32

typedef __bf16 bf16x8 __attribute__((ext_vector_type(8)));
typedef float  f32x4  __attribute__((ext_vector_type(4)));

typedef const __attribute__((address_space(1))) void* gas_ptr;
typedef __attribute__((address_space(3))) void* las_ptr;

__device__ __forceinline__ unsigned short f2bf(float f) {
    union { float f; unsigned u; } a; a.f = f;
    unsigned r = a.u + 0x7FFFu + ((a.u >> 16) & 1u);  // RNE
    return (unsigned short)(r >> 16);
}

// ---------------- prescale: t_bf16 = logmap0(x) -----------------------------
__global__ __launch_bounds__(256) void prescale_kernel(const float* __restrict__ x,
                                                       unsigned short* __restrict__ t) {
    __shared__ float red[4];
    const int row = blockIdx.x;
    const int tid = threadIdx.x;
    const float* xr = x + (size_t)row * GK;
    float v[16];
    float ss = 0.f;
#pragma unroll
    for (int j = 0; j < 4; ++j) {
        f32x4 p = *(const f32x4*)(xr + (size_t)(tid + j * 256) * 4);
#pragma unroll
        for (int e = 0; e < 4; ++e) { v[j * 4 + e] = p[e]; ss += p[e] * p[e]; }
    }
#pragma unroll
    for (int off = 32; off; off >>= 1) ss += __shfl_down(ss, off);
    if ((tid & 63) == 0) red[tid >> 6] = ss;
    __syncthreads();
    ss = red[0] + red[1] + red[2] + red[3];
    const float n = fmaxf(sqrtf(ss), 1e-15f);
    const float scale = atanhf(fminf(n, 1.f - 1e-7f)) / n;
    unsigned short* tr = t + (size_t)row * GK;
#pragma unroll
    for (int j = 0; j < 4; ++j) {
        ushort4 o;
        o.x = f2bf(v[j * 4 + 0] * scale);
        o.y = f2bf(v[j * 4 + 1] * scale);
        o.z = f2bf(v[j * 4 + 2] * scale);
        o.w = f2bf(v[j * 4 + 3] * scale);
        *(ushort4*)(tr + (size_t)(tid + j * 256) * 4) = o;
    }
}

// ---------------- W fp32 -> bf16 --------------------------------------------
__global__ __launch_bounds__(256) void convw_kernel(const float* __restrict__ W,
                                                    unsigned short* __restrict__ Wb) {
    const size_t i = (size_t)blockIdx.x * 256 + threadIdx.x;
    f32x4 p = *(const f32x4*)(W + i * 4);
    ushort4 o;
    o.x = f2bf(p[0]); o.y = f2bf(p[1]); o.z = f2bf(p[2]); o.w = f2bf(p[3]);
    *(ushort4*)(Wb + i * 4) = o;
}

// ---------------- GEMM: C[M,N] = A[M,K] * B[N,K]^T  (bf16 in, f32 out) ------
// m97 structure: 128x128 tile, BK=32, global_load_lds width=16, 16x16x32 MFMA.
__global__ __launch_bounds__(256) void gemm_kernel(const unsigned short* __restrict__ A,
                                                   const unsigned short* __restrict__ B,
                                                   float* __restrict__ C) {
    __shared__ __align__(16) unsigned short lA[BM * BK];  // 8 KB, row-major [128][32]
    __shared__ __align__(16) unsigned short lB[BN * BK];  // 8 KB

    const int tid  = threadIdx.x;
    const int wave = tid >> 6;
    const int lane = tid & 63;
    const int m16  = lane & 15;
    const int quad = lane >> 4;
    const int waveM = (wave >> 1) * 64;
    const int waveN = (wave & 1) * 64;
    const int tileM = blockIdx.y * BM;
    const int tileN = blockIdx.x * BN;

    // staging: each 1KB chunk = 16 rows of 64B; lane -> row lane/4, kbyte (lane&3)*16
    const int rA = lane >> 2;
    const int kg = (lane & 3) * 8;   // element offset within row

    f32x4 acc[4][4] = {};

    for (int k0 = 0; k0 < GK; k0 += BK) {
#pragma unroll
        for (int c = 0; c < 2; ++c) {
            const int chunk = wave * 2 + c;              // 0..7
            const int row = chunk * 16 + rA;
            const unsigned short* g = A + (size_t)(tileM + row) * GK + k0 + kg;
            __builtin_amdgcn_global_load_lds((gas_ptr)g, (las_ptr)&lA[chunk * 512], 16, 0, 0);
        }
#pragma unroll
        for (int c = 0; c < 2; ++c) {
            const int chunk = wave * 2 + c;
            const int row = chunk * 16 + rA;
            const unsigned short* g = B + (size_t)(tileN + row) * GK + k0 + kg;
            __builtin_amdgcn_global_load_lds((gas_ptr)g, (las_ptr)&lB[chunk * 512], 16, 0, 0);
        }
        __syncthreads();

        bf16x8 af[4], bfr[4];
#pragma unroll
        for (int i = 0; i < 4; ++i) {
            af[i]  = *(const bf16x8*)&lA[(waveM + i * 16 + m16) * BK + quad * 8];
            bfr[i] = *(const bf16x8*)&lB[(waveN + i * 16 + m16) * BK + quad * 8];
        }
#pragma unroll
        for (int mi = 0; mi < 4; ++mi)
#pragma unroll
            for (int ni = 0; ni < 4; ++ni)
                acc[mi][ni] = __builtin_amdgcn_mfma_f32_16x16x32_bf16(af[mi], bfr[ni], acc[mi][ni], 0, 0, 0);
        __syncthreads();
    }

    // C/D layout: col = lane&15, row = quad*4 + reg  [verified m89/m91]
#pragma unroll
    for (int mi = 0; mi < 4; ++mi)
#pragma unroll
        for (int ni = 0; ni < 4; ++ni)
#pragma unroll
            for (int r = 0; r < 4; ++r) {
                const int row = tileM + waveM + mi * 16 + quad * 4 + r;
                const int col = tileN + waveN + ni * 16 + m16;
                C[(size_t)row * GN + col] = acc[mi][ni][r];
            }
}

// ---------------- fused epilogue (in place on C = d_out) --------------------
// u = C_row + b;  y = proj(expmap0(u));  t2 = tanh(logmap0(y));  out = proj(expmap0(t2))
__global__ __launch_bounds__(256) void epilogue_kernel(float* __restrict__ C,
                                                       const float* __restrict__ bias) {
    __shared__ float red1[4];
    __shared__ float red2[4];
    const int row = blockIdx.x;
    const int tid = threadIdx.x;
    float* cr = C + (size_t)row * GN;
    float u[16];
    float ss = 0.f;
#pragma unroll
    for (int j = 0; j < 4; ++j) {
        f32x4 p = *(const f32x4*)(cr + (size_t)(tid + j * 256) * 4);
        f32x4 bb = *(const f32x4*)(bias + (size_t)(tid + j * 256) * 4);
#pragma unroll
        for (int e = 0; e < 4; ++e) { float q = p[e] + bb[e]; u[j * 4 + e] = q; ss += q * q; }
    }
#pragma unroll
    for (int off = 32; off; off >>= 1) ss += __shfl_down(ss, off);
    if ((tid & 63) == 0) red1[tid >> 6] = ss;
    __syncthreads();
    ss = red1[0] + red1[1] + red1[2] + red1[3];

    const float n1 = fmaxf(sqrtf(ss), 1e-15f);
    const float ny = fminf(tanhf(n1), 0.996f);            // ||proj(expmap0(u))||
    // combined scale: y_i = u_i*ny/n1 ; l_i = y_i*atanh(ny)/ny  => l_i = u_i*g
    const float g = (ny / n1) * (atanhf(fminf(ny, 1.f - 1e-7f)) / fmaxf(ny, 1e-15f));

    float t2[16];
    float ss2 = 0.f;
#pragma unroll
    for (int i = 0; i < 16; ++i) { float q = tanhf(u[i] * g); t2[i] = q; ss2 += q * q; }
#pragma unroll
    for (int off = 32; off; off >>= 1) ss2 += __shfl_down(ss2, off);
    if ((tid & 63) == 0) red2[tid >> 6] = ss2;
    __syncthreads();
    ss2 = red2[0] + red2[1] + red2[2] + red2[3];

    const float n3 = fmaxf(sqrtf(ss2), 1e-15f);
    const float s3 = fminf(tanhf(n3), 0.996f) / n3;
#pragma unroll
    for (int j = 0; j < 4; ++j) {
        f32x4 o;
#pragma unroll
        for (int e = 0; e < 4; ++e) o[e] = t2[j * 4 + e] * s3;
        *(f32x4*)(cr + (size_t)(tid + j * 256) * 4) = o;
    }
}

extern "C" void kernel_launch(void* const* d_in, const int* in_sizes, int n_in,
                              void* d_out, int out_size, void* d_ws, size_t ws_size,
                              hipStream_t stream) {
    const float* x = (const float*)d_in[0];
    const float* W = (const float*)d_in[1];
    const float* b = (const float*)d_in[2];
    float* out = (float*)d_out;

    // ws layout: t_bf16 [8192*4096] (64 MB) | W_bf16 [4096*4096] (32 MB)
    unsigned short* t_bf = (unsigned short*)d_ws;
    unsigned short* W_bf = t_bf + (size_t)GM * GK;

    prescale_kernel<<<GM, 256, 0, stream>>>(x, t_bf);
    convw_kernel<<<((size_t)GN * GK) / (256 * 4), 256, 0, stream>>>(W, W_bf);
    gemm_kernel<<<dim3(GN / BN, GM / BM), 256, 0, stream>>>(t_bf, W_bf, out);
    epilogue_kernel<<<GM, 256, 0, stream>>>(out, b);
}

// Round 3
// 590.258 us; speedup vs baseline: 1.1821x; 1.1821x over previous
//
#include <hip/hip_runtime.h>
#include <stdint.h>
#include <math.h>

#define GM 8192   // rows of x / out
#define GN 4096   // D_OUT
#define GK 4096   // D_IN
#define BM 128
#define BN 128
#define BK 32

typedef __bf16 bf16x8 __attribute__((ext_vector_type(8)));
typedef float  f32x4  __attribute__((ext_vector_type(4)));

typedef const __attribute__((address_space(1))) void* gas_ptr;
typedef __attribute__((address_space(3))) void* las_ptr;

__device__ __forceinline__ unsigned short f2bf(float f) {
    union { float f; unsigned u; } a; a.f = f;
    unsigned r = a.u + 0x7FFFu + ((a.u >> 16) & 1u);  // RNE
    return (unsigned short)(r >> 16);
}

// fast tanh via v_exp_f32; |err| ~1e-7 abs for |x|<~1, exact saturation for big x
__device__ __forceinline__ float fast_tanh(float x) {
    float xc = fminf(fmaxf(x, -15.f), 15.f);
    float e = __expf(2.f * xc);
    return (e - 1.f) * __builtin_amdgcn_rcpf(e + 1.f);
}
// fast atanh for 0 <= x <= 0.996
__device__ __forceinline__ float fast_atanh(float x) {
    return 0.5f * __logf((1.f + x) * __builtin_amdgcn_rcpf(1.f - x));
}

// ------- merged pre-pass: blocks [0,8192) prescale x rows; [8192,12288) cast W rows
__global__ __launch_bounds__(256) void pre_kernel(const float* __restrict__ x,
                                                  const float* __restrict__ W,
                                                  unsigned short* __restrict__ t,
                                                  unsigned short* __restrict__ Wb) {
    const int b = blockIdx.x;
    const int tid = threadIdx.x;
    if (b < GM) {
        __shared__ float red[4];
        const float* xr = x + (size_t)b * GK;
        float v[16];
        float ss = 0.f;
#pragma unroll
        for (int j = 0; j < 4; ++j) {
            f32x4 p = *(const f32x4*)(xr + (size_t)(tid + j * 256) * 4);
#pragma unroll
            for (int e = 0; e < 4; ++e) { v[j * 4 + e] = p[e]; ss += p[e] * p[e]; }
        }
#pragma unroll
        for (int off = 32; off; off >>= 1) ss += __shfl_down(ss, off);
        if ((tid & 63) == 0) red[tid >> 6] = ss;
        __syncthreads();
        ss = red[0] + red[1] + red[2] + red[3];
        const float n = fmaxf(sqrtf(ss), 1e-15f);
        const float scale = fast_atanh(fminf(n, 1.f - 1e-7f)) * __builtin_amdgcn_rcpf(n);
        unsigned short* tr = t + (size_t)b * GK;
#pragma unroll
        for (int j = 0; j < 4; ++j) {
            ushort4 o;
            o.x = f2bf(v[j * 4 + 0] * scale);
            o.y = f2bf(v[j * 4 + 1] * scale);
            o.z = f2bf(v[j * 4 + 2] * scale);
            o.w = f2bf(v[j * 4 + 3] * scale);
            *(ushort4*)(tr + (size_t)(tid + j * 256) * 4) = o;
        }
    } else {
        const int r = b - GM;
        const float* wr = W + (size_t)r * GK;
        unsigned short* wo = Wb + (size_t)r * GK;
#pragma unroll
        for (int j = 0; j < 4; ++j) {
            f32x4 p = *(const f32x4*)(wr + (size_t)(tid + j * 256) * 4);
            ushort4 o;
            o.x = f2bf(p[0]); o.y = f2bf(p[1]); o.z = f2bf(p[2]); o.w = f2bf(p[3]);
            *(ushort4*)(wo + (size_t)(tid + j * 256) * 4) = o;
        }
    }
}

// ---------------- GEMM: C[M,N] = A[M,K] * B[N,K]^T  (bf16 in, f32 out) ------
// m97 structure: 128x128 tile, BK=32, global_load_lds width=16, 16x16x32 MFMA.
// __launch_bounds__(256,4): force <=128 regs/wave so 4 blocks/CU resident ->
// grid 2048 runs in exactly 2 scheduling rounds (no ragged tail).
// NOTE: each global_load_lds chunk = 64 lanes x 16 B = 1024 BYTES; second
// chunk dest must be +1024 bytes (round-2 bug was +512 -> corrupted tiles).
__global__ __launch_bounds__(256, 4) void gemm_kernel(const unsigned short* __restrict__ A,
                                                      const unsigned short* __restrict__ B,
                                                      float* __restrict__ C) {
    __shared__ __align__(16) unsigned short lA[BM * BK];  // 8 KB, row-major [128][32]
    __shared__ __align__(16) unsigned short lB[BN * BK];  // 8 KB

    const int tid  = threadIdx.x;
    const int wave = tid >> 6;
    const int lane = tid & 63;
    const int m16  = lane & 15;
    const int quad = lane >> 4;
    const int waveM = (wave >> 1) * 64;
    const int waveN = (wave & 1) * 64;
    const int tileM = blockIdx.y * BM;
    const int tileN = blockIdx.x * BN;

    // staging: chunk = 1KB = 16 rows x 64B; lane -> row lane/4, elem-group (lane&3)*8
    const int rA = lane >> 2;
    const int kg = (lane & 3) * 8;

    const unsigned short* aPtr = A + (size_t)(tileM + wave * 32 + rA) * GK + kg;
    const unsigned short* bPtr = B + (size_t)(tileN + wave * 32 + rA) * GK + kg;
    las_ptr ldsA = (las_ptr)&lA[wave * 1024];   // wave base: 2048 bytes apart
    las_ptr ldsB = (las_ptr)&lB[wave * 1024];

    f32x4 acc[4][4] = {};

#pragma unroll 1
    for (int k0 = 0; k0 < GK; k0 += BK) {
        __builtin_amdgcn_global_load_lds((gas_ptr)(aPtr + k0),                    ldsA, 16, 0, 0);
        __builtin_amdgcn_global_load_lds((gas_ptr)(aPtr + k0 + (size_t)16 * GK),  (las_ptr)((char*)ldsA + 1024), 16, 0, 0);
        __builtin_amdgcn_global_load_lds((gas_ptr)(bPtr + k0),                    ldsB, 16, 0, 0);
        __builtin_amdgcn_global_load_lds((gas_ptr)(bPtr + k0 + (size_t)16 * GK),  (las_ptr)((char*)ldsB + 1024), 16, 0, 0);
        __syncthreads();

        bf16x8 af[4], bfr[4];
#pragma unroll
        for (int i = 0; i < 4; ++i) {
            af[i]  = *(const bf16x8*)&lA[(waveM + i * 16 + m16) * BK + quad * 8];
            bfr[i] = *(const bf16x8*)&lB[(waveN + i * 16 + m16) * BK + quad * 8];
        }
#pragma unroll
        for (int mi = 0; mi < 4; ++mi)
#pragma unroll
            for (int ni = 0; ni < 4; ++ni)
                acc[mi][ni] = __builtin_amdgcn_mfma_f32_16x16x32_bf16(af[mi], bfr[ni], acc[mi][ni], 0, 0, 0);
        __syncthreads();
    }

    // C/D layout: col = lane&15, row = quad*4 + reg  [verified m89/m91]
#pragma unroll
    for (int mi = 0; mi < 4; ++mi)
#pragma unroll
        for (int ni = 0; ni < 4; ++ni)
#pragma unroll
            for (int r = 0; r < 4; ++r) {
                const int row = tileM + waveM + mi * 16 + quad * 4 + r;
                const int col = tileN + waveN + ni * 16 + m16;
                C[(size_t)row * GN + col] = acc[mi][ni][r];
            }
}

// ---------------- fused epilogue (in place on C = d_out) --------------------
// u = C_row + b;  y = proj(expmap0(u));  t2 = tanh(logmap0(y));  out = proj(expmap0(t2))
__global__ __launch_bounds__(256) void epilogue_kernel(float* __restrict__ C,
                                                       const float* __restrict__ bias) {
    __shared__ float red1[4];
    __shared__ float red2[4];
    const int row = blockIdx.x;
    const int tid = threadIdx.x;
    float* cr = C + (size_t)row * GN;
    float u[16];
    float ss = 0.f;
#pragma unroll
    for (int j = 0; j < 4; ++j) {
        f32x4 p = *(const f32x4*)(cr + (size_t)(tid + j * 256) * 4);
        f32x4 bb = *(const f32x4*)(bias + (size_t)(tid + j * 256) * 4);
#pragma unroll
        for (int e = 0; e < 4; ++e) { float q = p[e] + bb[e]; u[j * 4 + e] = q; ss += q * q; }
    }
#pragma unroll
    for (int off = 32; off; off >>= 1) ss += __shfl_down(ss, off);
    if ((tid & 63) == 0) red1[tid >> 6] = ss;
    __syncthreads();
    ss = red1[0] + red1[1] + red1[2] + red1[3];

    const float n1 = fmaxf(sqrtf(ss), 1e-15f);
    const float ny = fminf(fast_tanh(n1), 0.996f);        // ||proj(expmap0(u))||
    // combined: y_i = u_i*ny/n1 ; l_i = y_i*atanh(ny)/ny  => l_i = u_i*g
    const float g = (ny * __builtin_amdgcn_rcpf(n1)) *
                    (fast_atanh(ny) * __builtin_amdgcn_rcpf(fmaxf(ny, 1e-15f)));

    float t2[16];
    float ss2 = 0.f;
#pragma unroll
    for (int i = 0; i < 16; ++i) { float q = fast_tanh(u[i] * g); t2[i] = q; ss2 += q * q; }
#pragma unroll
    for (int off = 32; off; off >>= 1) ss2 += __shfl_down(ss2, off);
    if ((tid & 63) == 0) red2[tid >> 6] = ss2;
    __syncthreads();
    ss2 = red2[0] + red2[1] + red2[2] + red2[3];

    const float n3 = fmaxf(sqrtf(ss2), 1e-15f);
    const float s3 = fminf(fast_tanh(n3), 0.996f) * __builtin_amdgcn_rcpf(n3);
#pragma unroll
    for (int j = 0; j < 4; ++j) {
        f32x4 o;
#pragma unroll
        for (int e = 0; e < 4; ++e) o[e] = t2[j * 4 + e] * s3;
        *(f32x4*)(cr + (size_t)(tid + j * 256) * 4) = o;
    }
}

extern "C" void kernel_launch(void* const* d_in, const int* in_sizes, int n_in,
                              void* d_out, int out_size, void* d_ws, size_t ws_size,
                              hipStream_t stream) {
    const float* x = (const float*)d_in[0];
    const float* W = (const float*)d_in[1];
    const float* b = (const float*)d_in[2];
    float* out = (float*)d_out;

    // ws layout: t_bf16 [8192*4096] (64 MB) | W_bf16 [4096*4096] (32 MB)
    unsigned short* t_bf = (unsigned short*)d_ws;
    unsigned short* W_bf = t_bf + (size_t)GM * GK;

    pre_kernel<<<GM + GN, 256, 0, stream>>>(x, W, t_bf, W_bf);
    gemm_kernel<<<dim3(GN / BN, GM / BM), 256, 0, stream>>>(t_bf, W_bf, out);
    epilogue_kernel<<<GM, 256, 0, stream>>>(out, b);
}

// Round 4
// 590.244 us; speedup vs baseline: 1.1822x; 1.0000x over previous
//
#include <hip/hip_runtime.h>
#include <stdint.h>
#include <math.h>

#define GM 8192   // rows of x / out
#define GN 4096   // D_OUT
#define GK 4096   // D_IN
#define BM 128
#define BN 128
#define BK 32

typedef __bf16 bf16x8 __attribute__((ext_vector_type(8)));
typedef float  f32x4  __attribute__((ext_vector_type(4)));

typedef const __attribute__((address_space(1))) void* gas_ptr;
typedef __attribute__((address_space(3))) void* las_ptr;

__device__ __forceinline__ unsigned short f2bf(float f) {
    union { float f; unsigned u; } a; a.f = f;
    unsigned r = a.u + 0x7FFFu + ((a.u >> 16) & 1u);  // RNE
    return (unsigned short)(r >> 16);
}
__device__ __forceinline__ float bf2f(unsigned short h) {
    union { unsigned u; float f; } a; a.u = ((unsigned)h) << 16;
    return a.f;
}

// fast tanh via v_exp_f32; |err| ~1e-7 abs, exact saturation for big x
__device__ __forceinline__ float fast_tanh(float x) {
    float xc = fminf(fmaxf(x, -15.f), 15.f);
    float e = __expf(2.f * xc);
    return (e - 1.f) * __builtin_amdgcn_rcpf(e + 1.f);
}
// fast atanh for 0 <= x <= 0.996
__device__ __forceinline__ float fast_atanh(float x) {
    return 0.5f * __logf((1.f + x) * __builtin_amdgcn_rcpf(1.f - x));
}

// ------- pre-pass, barrier-free: one WAVE per row ---------------------------
// blocks [0,2048): x rows (4 rows/block, 1/wave, logmap0 prescale -> bf16)
// blocks [2048,3072): W rows (4 rows/block, 1/wave, f32 -> bf16 stream cast)
__global__ __launch_bounds__(256) void pre_kernel(const float* __restrict__ x,
                                                  const float* __restrict__ W,
                                                  unsigned short* __restrict__ t,
                                                  unsigned short* __restrict__ Wb) {
    const int lane = threadIdx.x & 63;
    const int wv   = threadIdx.x >> 6;
    if (blockIdx.x < 2048) {
        const int row = blockIdx.x * 4 + wv;
        const float* xr = x + (size_t)row * GK;
        float v[64];
        float ss = 0.f;
#pragma unroll
        for (int j = 0; j < 16; ++j) {
            f32x4 p = *(const f32x4*)(xr + (size_t)(j * 64 + lane) * 4);
#pragma unroll
            for (int e = 0; e < 4; ++e) { v[j * 4 + e] = p[e]; ss += p[e] * p[e]; }
        }
#pragma unroll
        for (int off = 32; off; off >>= 1) ss += __shfl_xor(ss, off);
        const float n = fmaxf(sqrtf(ss), 1e-15f);
        const float scale = fast_atanh(fminf(n, 1.f - 1e-7f)) * __builtin_amdgcn_rcpf(n);
        unsigned short* tr = t + (size_t)row * GK;
#pragma unroll
        for (int j = 0; j < 16; ++j) {
            ushort4 o;
            o.x = f2bf(v[j * 4 + 0] * scale);
            o.y = f2bf(v[j * 4 + 1] * scale);
            o.z = f2bf(v[j * 4 + 2] * scale);
            o.w = f2bf(v[j * 4 + 3] * scale);
            *(ushort4*)(tr + (size_t)(j * 64 + lane) * 4) = o;
        }
    } else {
        const int row = (blockIdx.x - 2048) * 4 + wv;
        const float* wr = W + (size_t)row * GK;
        unsigned short* wo = Wb + (size_t)row * GK;
#pragma unroll 4
        for (int j = 0; j < 16; ++j) {
            f32x4 p = *(const f32x4*)(wr + (size_t)(j * 64 + lane) * 4);
            ushort4 o;
            o.x = f2bf(p[0]); o.y = f2bf(p[1]); o.z = f2bf(p[2]); o.w = f2bf(p[3]);
            *(ushort4*)(wo + (size_t)(j * 64 + lane) * 4) = o;
        }
    }
}

// ---------------- GEMM: C[M,N] = A[M,K] * B[N,K]^T  (bf16 in) ---------------
// m97 structure: 128x128 tile, BK=32, global_load_lds width=16, 16x16x32 MFMA.
// __launch_bounds__(256,4): 4 blocks/CU -> grid 2048 = exactly 2 rounds.
// BF16C: store C as bf16 into ws (saves 67 MB write + 67 MB epilogue read).
template <bool BF16C>
__global__ __launch_bounds__(256, 4) void gemm_kernel(const unsigned short* __restrict__ A,
                                                      const unsigned short* __restrict__ B,
                                                      void* __restrict__ Cv) {
    __shared__ __align__(16) unsigned short lA[BM * BK];  // 8 KB
    __shared__ __align__(16) unsigned short lB[BN * BK];  // 8 KB

    const int tid  = threadIdx.x;
    const int wave = tid >> 6;
    const int lane = tid & 63;
    const int m16  = lane & 15;
    const int quad = lane >> 4;
    const int waveM = (wave >> 1) * 64;
    const int waveN = (wave & 1) * 64;
    const int tileM = blockIdx.y * BM;
    const int tileN = blockIdx.x * BN;

    // staging: chunk = 64 lanes x 16 B = 1024 B = 16 rows x 64 B
    const int rA = lane >> 2;
    const int kg = (lane & 3) * 8;

    const unsigned short* aPtr = A + (size_t)(tileM + wave * 32 + rA) * GK + kg;
    const unsigned short* bPtr = B + (size_t)(tileN + wave * 32 + rA) * GK + kg;
    las_ptr ldsA = (las_ptr)&lA[wave * 1024];
    las_ptr ldsB = (las_ptr)&lB[wave * 1024];

    f32x4 acc[4][4] = {};

#pragma unroll 1
    for (int k0 = 0; k0 < GK; k0 += BK) {
        __builtin_amdgcn_global_load_lds((gas_ptr)(aPtr + k0),                   ldsA, 16, 0, 0);
        __builtin_amdgcn_global_load_lds((gas_ptr)(aPtr + k0 + (size_t)16 * GK), (las_ptr)((char*)ldsA + 1024), 16, 0, 0);
        __builtin_amdgcn_global_load_lds((gas_ptr)(bPtr + k0),                   ldsB, 16, 0, 0);
        __builtin_amdgcn_global_load_lds((gas_ptr)(bPtr + k0 + (size_t)16 * GK), (las_ptr)((char*)ldsB + 1024), 16, 0, 0);
        __syncthreads();

        bf16x8 af[4], bfr[4];
#pragma unroll
        for (int i = 0; i < 4; ++i) {
            af[i]  = *(const bf16x8*)&lA[(waveM + i * 16 + m16) * BK + quad * 8];
            bfr[i] = *(const bf16x8*)&lB[(waveN + i * 16 + m16) * BK + quad * 8];
        }
#pragma unroll
        for (int mi = 0; mi < 4; ++mi)
#pragma unroll
            for (int ni = 0; ni < 4; ++ni)
                acc[mi][ni] = __builtin_amdgcn_mfma_f32_16x16x32_bf16(af[mi], bfr[ni], acc[mi][ni], 0, 0, 0);
        __syncthreads();
    }

    // C/D layout: col = lane&15, row = quad*4 + reg  [verified m89/m91]
#pragma unroll
    for (int mi = 0; mi < 4; ++mi)
#pragma unroll
        for (int ni = 0; ni < 4; ++ni)
#pragma unroll
            for (int r = 0; r < 4; ++r) {
                const int row = tileM + waveM + mi * 16 + quad * 4 + r;
                const int col = tileN + waveN + ni * 16 + m16;
                if (BF16C)
                    ((unsigned short*)Cv)[(size_t)row * GN + col] = f2bf(acc[mi][ni][r]);
                else
                    ((float*)Cv)[(size_t)row * GN + col] = acc[mi][ni][r];
            }
}

// ---------------- fused epilogue, barrier-free: one WAVE per row ------------
// u = C_row + b;  y = proj(expmap0(u));  t2 = tanh(logmap0(y));  out = proj(expmap0(t2))
template <bool BF16C>
__global__ __launch_bounds__(256) void epilogue_kernel(const void* __restrict__ Cv,
                                                       const float* __restrict__ bias,
                                                       float* __restrict__ out) {
    const int lane = threadIdx.x & 63;
    const int row  = blockIdx.x * 4 + (threadIdx.x >> 6);
    float u[64];
    float ss = 0.f;
#pragma unroll
    for (int j = 0; j < 16; ++j) {
        const size_t col = (size_t)(j * 64 + lane) * 4;
        f32x4 bb = *(const f32x4*)(bias + col);
        if (BF16C) {
            ushort4 p = *(const ushort4*)((const unsigned short*)Cv + (size_t)row * GN + col);
            float q0 = bf2f(p.x) + bb[0], q1 = bf2f(p.y) + bb[1];
            float q2 = bf2f(p.z) + bb[2], q3 = bf2f(p.w) + bb[3];
            u[j * 4 + 0] = q0; u[j * 4 + 1] = q1; u[j * 4 + 2] = q2; u[j * 4 + 3] = q3;
            ss += q0 * q0 + q1 * q1 + q2 * q2 + q3 * q3;
        } else {
            f32x4 p = *(const f32x4*)((const float*)Cv + (size_t)row * GN + col);
#pragma unroll
            for (int e = 0; e < 4; ++e) { float q = p[e] + bb[e]; u[j * 4 + e] = q; ss += q * q; }
        }
    }
#pragma unroll
    for (int off = 32; off; off >>= 1) ss += __shfl_xor(ss, off);

    const float n1 = fmaxf(sqrtf(ss), 1e-15f);
    const float ny = fminf(fast_tanh(n1), 0.996f);        // ||proj(expmap0(u))||
    // combined: y_i = u_i*ny/n1 ; l_i = y_i*atanh(ny)/ny  => l_i = u_i*g
    const float g = (ny * __builtin_amdgcn_rcpf(n1)) *
                    (fast_atanh(ny) * __builtin_amdgcn_rcpf(fmaxf(ny, 1e-15f)));

    float ss2 = 0.f;
#pragma unroll
    for (int i = 0; i < 64; ++i) { float q = fast_tanh(u[i] * g); u[i] = q; ss2 += q * q; }
#pragma unroll
    for (int off = 32; off; off >>= 1) ss2 += __shfl_xor(ss2, off);

    const float n3 = fmaxf(sqrtf(ss2), 1e-15f);
    const float s3 = fminf(fast_tanh(n3), 0.996f) * __builtin_amdgcn_rcpf(n3);
    float* orow = out + (size_t)row * GN;
#pragma unroll
    for (int j = 0; j < 16; ++j) {
        f32x4 o;
#pragma unroll
        for (int e = 0; e < 4; ++e) o[e] = u[j * 4 + e] * s3;
        *(f32x4*)(orow + (size_t)(j * 64 + lane) * 4) = o;
    }
}

extern "C" void kernel_launch(void* const* d_in, const int* in_sizes, int n_in,
                              void* d_out, int out_size, void* d_ws, size_t ws_size,
                              hipStream_t stream) {
    const float* x = (const float*)d_in[0];
    const float* W = (const float*)d_in[1];
    const float* b = (const float*)d_in[2];
    float* out = (float*)d_out;

    // ws layout: t_bf16 (64 MiB) | W_bf16 (32 MiB) | [optional] C_bf16 (64 MiB)
    unsigned short* t_bf = (unsigned short*)d_ws;
    unsigned short* W_bf = t_bf + (size_t)GM * GK;
    unsigned short* C_bf = W_bf + (size_t)GN * GK;
    const size_t need_bf16c = ((size_t)GM * GK + (size_t)GN * GK + (size_t)GM * GN) * 2;
    const bool bf16c = ws_size >= need_bf16c;   // ws_size fixed -> same path every call

    pre_kernel<<<2048 + 1024, 256, 0, stream>>>(x, W, t_bf, W_bf);
    if (bf16c) {
        gemm_kernel<true><<<dim3(GN / BN, GM / BM), 256, 0, stream>>>(t_bf, W_bf, (void*)C_bf);
        epilogue_kernel<true><<<2048, 256, 0, stream>>>((const void*)C_bf, b, out);
    } else {
        gemm_kernel<false><<<dim3(GN / BN, GM / BM), 256, 0, stream>>>(t_bf, W_bf, (void*)out);
        epilogue_kernel<false><<<2048, 256, 0, stream>>>((const void*)out, b, out);
    }
}